// Round 8
// baseline (236.909 us; speedup 1.0000x reference)
//
#include <hip/hip_runtime.h>
#include <hip/hip_bf16.h>
#include <cstdint>
#include <cstddef>

#define B_ 8
#define N_ 4096
#define DIM_ 768
#define H_ 12
#define M_ (B_*N_)        // 32768
#define SCALE_ 0.125f
#define NS2 16
#define KDIM 768
#define NKT 12
#define NITER 6
#define QKS 1536          // qk row stride (q,k only)

typedef __attribute__((ext_vector_type(8))) short s8v;
typedef __attribute__((ext_vector_type(4))) float f4v;

__device__ inline float bf2f(unsigned short u) {
    unsigned v = ((unsigned)u) << 16;
    return __builtin_bit_cast(float, v);
}
__device__ inline unsigned short f2bf(float f) {
    unsigned u = __builtin_bit_cast(unsigned, f);
    return (unsigned short)((u + 0x7FFFu + ((u >> 16) & 1u)) >> 16);
}
__device__ inline void gload16(const void* g, void* l) {
    __builtin_amdgcn_global_load_lds(
        (const __attribute__((address_space(1))) void*)g,
        (__attribute__((address_space(3))) void*)l, 16, 0, 0);
}

#define BARX() __builtin_amdgcn_s_barrier()
#define PRIO1() __builtin_amdgcn_s_setprio(1)
#define PRIO0() __builtin_amdgcn_s_setprio(0)
#define VM4() asm volatile("s_waitcnt vmcnt(4)" ::: "memory")
#define VM0() asm volatile("s_waitcnt vmcnt(0)" ::: "memory")

// ---------------- 256x256 8-phase bf16 GEMM: C = A[M,K] @ B[Nc,K]^T, bf16 out ---------
// EPI==0: qk GEMM with fused alpha-path partials in the epilogue (q cols = tn<3).
// EPI==2: batched weight GEMM (9 tiles per batch: M=768, ntn=3), A/C offset by
//         batch*DIM_*DIM_, B shared; no alpha epilogue.
template<int EPI>
__global__ __launch_bounds__(512, 2)
void gemm8(const unsigned short* __restrict__ A, int ldaE,
           const unsigned short* __restrict__ Bmat,
           unsigned short* __restrict__ Cb,
           const float* __restrict__ w_q,
           float* __restrict__ pv1, float* __restrict__ pms1,
           int Nc, int ntn)
{
    __shared__ __align__(16) char smem[131072];   // 2 bufs x 4 regions x 16KB
    const int tid = threadIdx.x;
    const int l = tid & 63, w = tid >> 6;
    const int lr = l & 15, g = l >> 4;
    const int wm = w >> 2, wn = w & 3;

    const int nwg = gridDim.x, cpx = nwg >> 3;
    const int bid = blockIdx.x;
    int lg = (bid & 7) * cpx + (bid >> 3);

    size_t batch_off = 0;
    if (EPI == 2) {
        const int bb = lg / 9;
        lg -= bb * 9;
        batch_off = (size_t)bb * (DIM_ * DIM_);
    }
    const int tm = lg / ntn, tn = lg % ntn;
    const int m0 = tm * 256, n0 = tn * 256;

    const long ldaB = (long)ldaE * 2;
    const long ldbB = (long)KDIM * 2;

    const int srA = w * 8 + (l >> 3);
    const int kbs = (l & 7) * 16;
    const int kbx = kbs ^ ((srA & 7) << 4);
    long offA[2], offB[2];
    offA[0] = (long)(srA) * ldaB + kbx;
    offA[1] = (long)(128 + srA) * ldaB + kbx;
    offB[0] = (long)(((srA >> 5)) * 64 + (srA & 31)) * ldbB + kbx;
    offB[1] = (long)((2 + (srA >> 5)) * 64 + (srA & 31)) * ldbB + kbx;

    const char* Abase = (const char*)(A + batch_off + (size_t)m0 * ldaE);
    const char* Bbase = (const char*)(Bmat + (size_t)n0 * KDIM);

    const int aoff = (wm * 64 + lr) * 128;
    const int boff = (wn * 32 + lr) * 128;
    const int kx0 = (g * 16) ^ ((lr & 7) << 4);
    const int kx1 = (64 + g * 16) ^ ((lr & 7) << 4);

    f4v acc[8][4] = {};
    s8v af[4][2];
    s8v bfr[2][2][2];

#define STG_A(buf_, qm_, kt_) { \
    const char* s0_ = Abase + (long)(kt_) * 2 + (long)(qm_) * 64 * ldaB; \
    char* d0_ = smem + ((buf_) * 4 + (qm_)) * 16384 + w * 1024; \
    gload16(s0_ + offA[0], d0_); \
    gload16(s0_ + offA[1], d0_ + 8192); }

#define STG_B(buf_, qn_, kt_) { \
    const char* s0_ = Bbase + (long)(kt_) * 2 + (long)(qn_) * 32 * ldbB; \
    char* d0_ = smem + ((buf_) * 4 + 2 + (qn_)) * 16384 + w * 1024; \
    gload16(s0_ + offB[0], d0_); \
    gload16(s0_ + offB[1], d0_ + 8192); }

#define DS_A(buf_, qm_) { \
    const char* ba_ = smem + ((buf_) * 4 + (qm_)) * 16384 + aoff; \
    af[0][0] = *(const s8v*)(ba_ +    0 + kx0); af[0][1] = *(const s8v*)(ba_ +    0 + kx1); \
    af[1][0] = *(const s8v*)(ba_ + 2048 + kx0); af[1][1] = *(const s8v*)(ba_ + 2048 + kx1); \
    af[2][0] = *(const s8v*)(ba_ + 4096 + kx0); af[2][1] = *(const s8v*)(ba_ + 4096 + kx1); \
    af[3][0] = *(const s8v*)(ba_ + 6144 + kx0); af[3][1] = *(const s8v*)(ba_ + 6144 + kx1); }

#define DS_B(buf_, qn_) { \
    const char* bb_ = smem + ((buf_) * 4 + 2 + (qn_)) * 16384 + boff; \
    bfr[qn_][0][0] = *(const s8v*)(bb_ +    0 + kx0); bfr[qn_][0][1] = *(const s8v*)(bb_ +    0 + kx1); \
    bfr[qn_][1][0] = *(const s8v*)(bb_ + 2048 + kx0); bfr[qn_][1][1] = *(const s8v*)(bb_ + 2048 + kx1); }

#define MM(fmg_, fng_, qn_, kk_) \
    acc[fmg_][fng_] = __builtin_amdgcn_mfma_f32_16x16x32_bf16(af[(fmg_)&3][kk_], bfr[qn_][(fng_)&1][kk_], acc[fmg_][fng_], 0, 0, 0);

#define MFMA8(qm_, qn_, kk_) \
    MM((qm_)*4+0, (qn_)*2+0, qn_, kk_) MM((qm_)*4+0, (qn_)*2+1, qn_, kk_) \
    MM((qm_)*4+1, (qn_)*2+0, qn_, kk_) MM((qm_)*4+1, (qn_)*2+1, qn_, kk_) \
    MM((qm_)*4+2, (qn_)*2+0, qn_, kk_) MM((qm_)*4+2, (qn_)*2+1, qn_, kk_) \
    MM((qm_)*4+3, (qn_)*2+0, qn_, kk_) MM((qm_)*4+3, (qn_)*2+1, qn_, kk_)

#define MFMA16(qm_, qn_) { MFMA8(qm_, qn_, 0) MFMA8(qm_, qn_, 1) }

    STG_A(0, 0, 0); STG_B(0, 0, 0); STG_A(0, 1, 0); STG_B(0, 1, 0);
    STG_A(1, 0, 64); STG_B(1, 0, 64);
    VM4(); BARX();

    for (int i = 0; i < NITER; ++i) {
        const int t1k = (2 * i + 1) * 64, t2k = (2 * i + 2) * 64, t3k = (2 * i + 3) * 64;
        const bool h2 = (2 * i + 2) < NKT, h3 = (2 * i + 3) < NKT;
        const bool last = (i == NITER - 1);
        DS_A(0, 0); DS_B(0, 0); STG_B(1, 1, t1k);
        BARX(); PRIO1(); MFMA16(0, 0); PRIO0(); BARX();
        DS_B(0, 1); STG_A(1, 1, t1k);
        BARX(); PRIO1(); MFMA16(0, 1); PRIO0(); BARX();
        DS_A(0, 1); if (h2) STG_A(0, 0, t2k);
        BARX(); PRIO1(); MFMA16(1, 0); PRIO0(); BARX();
        if (h2) STG_B(0, 0, t2k);
        BARX(); PRIO1(); MFMA16(1, 1); PRIO0();
        if (last) { VM0(); } else { VM4(); }
        BARX();
        DS_A(1, 0); DS_B(1, 0); if (h2) STG_A(0, 1, t2k);
        BARX(); PRIO1(); MFMA16(0, 0); PRIO0(); BARX();
        DS_B(1, 1); if (h2) STG_B(0, 1, t2k);
        BARX(); PRIO1(); MFMA16(0, 1); PRIO0(); BARX();
        DS_A(1, 1); if (h3) STG_A(1, 0, t3k);
        BARX(); PRIO1(); MFMA16(1, 0); PRIO0(); BARX();
        if (h3) STG_B(1, 0, t3k);
        BARX(); PRIO1(); MFMA16(1, 1); PRIO0();
        if (last) { VM0(); } else { VM4(); }
        BARX();
    }

    // C store
#pragma unroll
    for (int fmg = 0; fmg < 8; ++fmg) {
#pragma unroll
        for (int fng = 0; fng < 4; ++fng) {
            const int col = n0 + wn * 64 + fng * 16 + lr;
#pragma unroll
            for (int r = 0; r < 4; ++r) {
                const int row = m0 + wm * 128 + fmg * 16 + g * 4 + r;
                Cb[batch_off + (size_t)row * Nc + col] = f2bf(acc[fmg][fng][r]);
            }
        }
    }

    // fused alpha partials: q columns only (tn<3); each wave = one head x 128 rows
    if (EPI == 0 && tn < 3) {
        const int h = tn * 4 + wn;
        float wq[4];
#pragma unroll
        for (int f = 0; f < 4; ++f) wq[f] = w_q[h * 64 + f * 16 + lr];

        float d[8][4];
#pragma unroll
        for (int fmg = 0; fmg < 8; ++fmg) {
#pragma unroll
            for (int r = 0; r < 4; ++r) {
                float s = acc[fmg][0][r] * wq[0] + acc[fmg][1][r] * wq[1]
                        + acc[fmg][2][r] * wq[2] + acc[fmg][3][r] * wq[3];
                s += __shfl_xor(s, 1); s += __shfl_xor(s, 2);
                s += __shfl_xor(s, 4); s += __shfl_xor(s, 8);
                d[fmg][r] = s * SCALE_;
            }
        }
        float mw = d[0][0];
#pragma unroll
        for (int fmg = 0; fmg < 8; ++fmg)
#pragma unroll
            for (int r = 0; r < 4; ++r) mw = fmaxf(mw, d[fmg][r]);
        mw = fmaxf(mw, __shfl_xor(mw, 16));
        mw = fmaxf(mw, __shfl_xor(mw, 32));

        float ssum = 0.f;
        float pvec[4] = {};
#pragma unroll
        for (int fmg = 0; fmg < 8; ++fmg) {
#pragma unroll
            for (int r = 0; r < 4; ++r) {
                const float e = __expf(d[fmg][r] - mw);
                ssum += e;
#pragma unroll
                for (int f = 0; f < 4; ++f) pvec[f] += e * acc[fmg][f][r];
            }
        }
        ssum += __shfl_xor(ssum, 16); ssum += __shfl_xor(ssum, 32);
#pragma unroll
        for (int f = 0; f < 4; ++f) {
            pvec[f] += __shfl_xor(pvec[f], 16);
            pvec[f] += __shfl_xor(pvec[f], 32);
        }

        const int b = m0 >> 12;
        const int bh = b * H_ + h;
        const int slice = ((m0 & (N_ - 1)) >> 7) + wm;   // 32 slices per bh
        if (g == 0) {
#pragma unroll
            for (int f = 0; f < 4; ++f)
                pv1[(size_t)(bh * 32 + slice) * 64 + f * 16 + lr] = pvec[f];
            if (lr == 0) {
                pms1[(bh * 32 + slice) * 2] = mw;
                pms1[(bh * 32 + slice) * 2 + 1] = ssum;
            }
        }
    }
#undef STG_A
#undef STG_B
#undef DS_A
#undef DS_B
#undef MM
#undef MFMA8
#undef MFMA16
}

// ---------------- 128x256 4-phase bf16 GEMM, f32 epilogue (out GEMM) ----------------
// Cf[row,col] = A@B_b^T + bias[col] + bf2f(Qf[row*QKS+col]); B_b per batch (row/4096).
__global__ __launch_bounds__(512, 2)
void gemm128(const unsigned short* __restrict__ A, int ldaE,
             const unsigned short* __restrict__ Bmat,
             float* __restrict__ Cf,
             const float* __restrict__ bias, const unsigned short* __restrict__ Qf,
             int Nc, int ntn)
{
    __shared__ __align__(16) char smem[98304];
    const int tid = threadIdx.x;
    const int l = tid & 63, w = tid >> 6;
    const int lr = l & 15, g = l >> 4;
    const int wm = w >> 2, wn = w & 3;

    const int nwg = gridDim.x, cpx = nwg >> 3;
    const int bid = blockIdx.x;
    const int lg = (bid & 7) * cpx + (bid >> 3);
    const int tm = lg / ntn, tn = lg % ntn;
    const int m0 = tm * 128, n0 = tn * 256;

    const long ldaB = (long)ldaE * 2;
    const long ldbB = (long)KDIM * 2;

    const unsigned short* Bp = Bmat + (size_t)(m0 >> 12) * (DIM_ * DIM_);

    const int srA = w * 8 + (l >> 3);
    const int kbs = (l & 7) * 16;
    const int kbx = kbs ^ ((srA & 7) << 4);
    long offA[2], offB[2];
    offA[0] = (long)(srA) * ldaB + kbx;
    offA[1] = (long)(64 + srA) * ldaB + kbx;
    offB[0] = (long)(((srA >> 5)) * 64 + (srA & 31)) * ldbB + kbx;
    offB[1] = (long)((2 + (srA >> 5)) * 64 + (srA & 31)) * ldbB + kbx;

    const char* Abase = (const char*)(A + (size_t)m0 * ldaE);
    const char* Bbase = (const char*)(Bp + (size_t)n0 * KDIM);

    const int aoff = (wm * 64 + lr) * 128;
    const int boff = (wn * 32 + lr) * 128;
    const int kx0 = (g * 16) ^ ((lr & 7) << 4);
    const int kx1 = (64 + g * 16) ^ ((lr & 7) << 4);

    f4v acc[4][4] = {};
    s8v af[4][2];
    s8v bfr[2][2][2];

#define STG_A1(buf_, kt_) { \
    const char* s0_ = Abase + (long)(kt_) * 2; \
    char* d0_ = smem + ((buf_) * 3) * 16384 + w * 1024; \
    gload16(s0_ + offA[0], d0_); \
    gload16(s0_ + offA[1], d0_ + 8192); }

#define STG_B1(buf_, qn_, kt_) { \
    const char* s0_ = Bbase + (long)(kt_) * 2 + (long)(qn_) * 32 * ldbB; \
    char* d0_ = smem + ((buf_) * 3 + 1 + (qn_)) * 16384 + w * 1024; \
    gload16(s0_ + offB[0], d0_); \
    gload16(s0_ + offB[1], d0_ + 8192); }

#define DS_A1(buf_) { \
    const char* ba_ = smem + ((buf_) * 3) * 16384 + aoff; \
    af[0][0] = *(const s8v*)(ba_ +    0 + kx0); af[0][1] = *(const s8v*)(ba_ +    0 + kx1); \
    af[1][0] = *(const s8v*)(ba_ + 2048 + kx0); af[1][1] = *(const s8v*)(ba_ + 2048 + kx1); \
    af[2][0] = *(const s8v*)(ba_ + 4096 + kx0); af[2][1] = *(const s8v*)(ba_ + 4096 + kx1); \
    af[3][0] = *(const s8v*)(ba_ + 6144 + kx0); af[3][1] = *(const s8v*)(ba_ + 6144 + kx1); }

#define DS_B1(buf_, qn_) { \
    const char* bb_ = smem + ((buf_) * 3 + 1 + (qn_)) * 16384 + boff; \
    bfr[qn_][0][0] = *(const s8v*)(bb_ +    0 + kx0); bfr[qn_][0][1] = *(const s8v*)(bb_ +    0 + kx1); \
    bfr[qn_][1][0] = *(const s8v*)(bb_ + 2048 + kx0); bfr[qn_][1][1] = *(const s8v*)(bb_ + 2048 + kx1); }

#define MM1(fm_, fng_, qn_, kk_) \
    acc[fm_][fng_] = __builtin_amdgcn_mfma_f32_16x16x32_bf16(af[fm_][kk_], bfr[qn_][(fng_)&1][kk_], acc[fm_][fng_], 0, 0, 0);

#define MFMA16_1(qn_, kk_) \
    MM1(0, (qn_)*2+0, qn_, kk_) MM1(0, (qn_)*2+1, qn_, kk_) \
    MM1(1, (qn_)*2+0, qn_, kk_) MM1(1, (qn_)*2+1, qn_, kk_) \
    MM1(2, (qn_)*2+0, qn_, kk_) MM1(2, (qn_)*2+1, qn_, kk_) \
    MM1(3, (qn_)*2+0, qn_, kk_) MM1(3, (qn_)*2+1, qn_, kk_)

#define MFMA32_1(qn_) { MFMA16_1(qn_, 0) MFMA16_1(qn_, 1) }

    STG_A1(0, 0); STG_B1(0, 0, 0); STG_B1(0, 1, 0);
    STG_A1(1, 64); STG_B1(1, 0, 64);
    VM4(); BARX();

    for (int i = 0; i < NITER; ++i) {
        const int t1k = (2 * i + 1) * 64, t2k = (2 * i + 2) * 64, t3k = (2 * i + 3) * 64;
        const bool h2 = (2 * i + 2) < NKT, h3 = (2 * i + 3) < NKT;
        const bool last = (i == NITER - 1);
        DS_A1(0); DS_B1(0, 0); STG_B1(1, 1, t1k);
        BARX(); PRIO1(); MFMA32_1(0); PRIO0(); BARX();
        DS_B1(0, 1); if (h2) { STG_A1(0, t2k); STG_B1(0, 0, t2k); }
        BARX(); PRIO1(); MFMA32_1(1); PRIO0();
        if (last) { VM0(); } else { VM4(); }
        BARX();
        DS_A1(1); DS_B1(1, 0); if (h2) STG_B1(0, 1, t2k);
        BARX(); PRIO1(); MFMA32_1(0); PRIO0(); BARX();
        DS_B1(1, 1); if (h3) { STG_A1(1, t3k); STG_B1(1, 0, t3k); }
        BARX(); PRIO1(); MFMA32_1(1); PRIO0();
        if (last) { VM0(); } else { VM4(); }
        BARX();
    }

#pragma unroll
    for (int fm = 0; fm < 4; ++fm) {
#pragma unroll
        for (int fng = 0; fng < 4; ++fng) {
            const int col = n0 + wn * 64 + fng * 16 + lr;
#pragma unroll
            for (int r = 0; r < 4; ++r) {
                const int row = m0 + wm * 64 + fm * 16 + g * 4 + r;
                Cf[(size_t)row * Nc + col] = acc[fm][fng][r] + bias[col]
                                             + bf2f(Qf[(size_t)row * QKS + col]);
            }
        }
    }
#undef STG_A1
#undef STG_B1
#undef DS_A1
#undef DS_B1
#undef MM1
#undef MFMA16_1
#undef MFMA32_1
}

// ---------------- beta path: softmax-weighted global vector partials ----------------
__global__ __launch_bounds__(256)
void fused_path(const unsigned short* __restrict__ qkv, int col_off,
                const float* __restrict__ vec, int per_bh,
                float* __restrict__ partv, float* __restrict__ partms)
{
    const int bid = blockIdx.x;
    const int bh = bid / NS2, sp = bid % NS2;
    const int b = bh / H_, h = bh % H_;
    const int t = threadIdx.x;
    const int lane8 = t & 7, grp = t >> 3;

    const unsigned short* base = qkv + ((size_t)(b * N_ + sp * 256) * QKS)
                                 + col_off + h * 64 + lane8 * 8;
    const float* wv = vec + (per_bh ? bh * 64 : h * 64) + lane8 * 8;
    float w8[8];
#pragma unroll
    for (int j = 0; j < 8; j++) w8[j] = wv[j];

    float q[8][8];
    float d[8];
#pragma unroll
    for (int pass = 0; pass < 8; ++pass) {
        const int row = pass * 32 + grp;
        s8v q8 = *(const s8v*)(base + (size_t)row * QKS);
        float s = 0.f;
#pragma unroll
        for (int j = 0; j < 8; j++) {
            q[pass][j] = bf2f((unsigned short)q8[j]);
            s += q[pass][j] * w8[j];
        }
        s += __shfl_xor(s, 1); s += __shfl_xor(s, 2); s += __shfl_xor(s, 4);
        d[pass] = s * SCALE_;
    }
    float m = d[0];
#pragma unroll
    for (int pass = 1; pass < 8; ++pass) m = fmaxf(m, d[pass]);
    float ssum = 0.f;
    float a8[8] = {};
#pragma unroll
    for (int pass = 0; pass < 8; ++pass) {
        float e = __expf(d[pass] - m);
        ssum += e;
#pragma unroll
        for (int j = 0; j < 8; j++) a8[j] += e * q[pass][j];
    }

    __shared__ float Lm[32], Ls[32];
    __shared__ float La[32][64];
    if (lane8 == 0) { Lm[grp] = m; Ls[grp] = ssum; }
#pragma unroll
    for (int j = 0; j < 8; j++) La[grp][lane8 * 8 + j] = a8[j];
    __syncthreads();

    if (t < 64) {
        float mstar = Lm[0];
#pragma unroll
        for (int g2 = 1; g2 < 32; ++g2) mstar = fmaxf(mstar, Lm[g2]);
        float sstar = 0.f, v = 0.f;
#pragma unroll
        for (int g2 = 0; g2 < 32; ++g2) {
            float e = __expf(Lm[g2] - mstar);
            sstar += Ls[g2] * e;
            v += La[g2][t] * e;
        }
        partv[(size_t)bid * 64 + t] = v;
        if (t == 0) { partms[bid * 2] = mstar; partms[bid * 2 + 1] = sstar; }
    }
}

// combine nsp partials per bh -> gout[bh][64]; optionally bvec = gout * wk[h]
__global__ void path_reduce(const float* __restrict__ partv, const float* __restrict__ partms,
                            int nsp, float* __restrict__ gout,
                            const float* __restrict__ wk, float* __restrict__ bvec)
{
    const int bh = blockIdx.x;
    const int t = threadIdx.x;   // 64
    const int h = bh % H_;
    float mstar = partms[(bh * nsp) * 2];
    for (int p = 1; p < nsp; ++p) mstar = fmaxf(mstar, partms[(bh * nsp + p) * 2]);
    float sstar = 0.f, v = 0.f;
    for (int p = 0; p < nsp; ++p) {
        float e = __expf(partms[(bh * nsp + p) * 2] - mstar);
        sstar += partms[(bh * nsp + p) * 2 + 1] * e;
        v += partv[(size_t)(bh * nsp + p) * 64 + t] * e;
    }
    float g = v / sstar;
    gout[bh * 64 + t] = g;
    if (wk) bvec[bh * 64 + t] = g * wk[h * 64 + t];
}

// ---------------- conversion: x -> xb, Wqk -> wqkb, Wv -> wvT (transposed) ----------
__global__ void cvt_all(const float* __restrict__ x, const float* __restrict__ Wqkv,
                        unsigned short* __restrict__ xb, unsigned short* __restrict__ wqkb,
                        unsigned short* __restrict__ wvT,
                        int n4x, int n4xw)
{
    int i = blockIdx.x * 256 + threadIdx.x;
    if (i < n4xw) {
        const float* src; unsigned short* dst; int k;
        if (i < n4x) { src = x; dst = xb; k = i; }
        else { src = Wqkv; dst = wqkb; k = i - n4x; }
        float4 v = ((const float4*)src)[k];
        ushort4 o;
        o.x = f2bf(v.x); o.y = f2bf(v.y); o.z = f2bf(v.z); o.w = f2bf(v.w);
        ((ushort4*)dst)[k] = o;
    } else {
        const int k = i - n4xw;
        const int ii = k % DIM_;
        const int c0 = (k / DIM_) * 4;
        ushort4 o;
        o.x = f2bf(Wqkv[(size_t)(2 * DIM_ + c0 + 0) * DIM_ + ii]);
        o.y = f2bf(Wqkv[(size_t)(2 * DIM_ + c0 + 1) * DIM_ + ii]);
        o.z = f2bf(Wqkv[(size_t)(2 * DIM_ + c0 + 2) * DIM_ + ii]);
        o.w = f2bf(Wqkv[(size_t)(2 * DIM_ + c0 + 3) * DIM_ + ii]);
        *(ushort4*)&wvT[(size_t)ii * DIM_ + c0] = o;
    }
}

// ---------------- fold gk into Wp: W2[b][j][c] = bf16(Wp[j][c] * gk[b*768+c]) --------
__global__ __launch_bounds__(256)
void fold_wp(const float* __restrict__ Wp, const float* __restrict__ gk,
             unsigned short* __restrict__ W2)
{
    int idx = blockIdx.x * 256 + threadIdx.x;
    int e4 = idx * 4;
    int b = (int)((unsigned)e4 / (unsigned)(DIM_ * DIM_));
    int rem = e4 - b * (DIM_ * DIM_);
    int c = rem % DIM_;
    float4 wv = *(const float4*)&Wp[rem];
    const float* gp = &gk[b * DIM_ + c];
    ushort4 o;
    o.x = f2bf(wv.x * gp[0]); o.y = f2bf(wv.y * gp[1]);
    o.z = f2bf(wv.z * gp[2]); o.w = f2bf(wv.w * gp[3]);
    *(ushort4*)&W2[e4] = o;
}

extern "C" void kernel_launch(void* const* d_in, const int* in_sizes, int n_in,
                              void* d_out, int out_size, void* d_ws, size_t ws_size,
                              hipStream_t stream)
{
    const float* x    = (const float*)d_in[0];
    const float* Wqkv = (const float*)d_in[1];
    const float* Wp   = (const float*)d_in[2];
    const float* bp   = (const float*)d_in[3];
    const float* w_q  = (const float*)d_in[4];
    const float* w_k  = (const float*)d_in[5];
    float* out = (float*)d_out;

    constexpr size_t NXB  = (size_t)M_ * DIM_;
    constexpr size_t NWQK = (size_t)2 * DIM_ * DIM_;
    constexpr size_t NWV  = (size_t)DIM_ * DIM_;
    constexpr size_t NQK  = (size_t)M_ * QKS;
    constexpr size_t NW2  = (size_t)B_ * DIM_ * DIM_;

    char* p = (char*)d_ws;
    unsigned short* xb    = (unsigned short*)p; p += NXB * 2;
    unsigned short* wqkb  = (unsigned short*)p; p += NWQK * 2;
    unsigned short* wvT   = (unsigned short*)p; p += NWV * 2;
    unsigned short* qkb   = (unsigned short*)p; p += NQK * 2;
    unsigned short* w2b   = (unsigned short*)p; p += NW2 * 2;
    unsigned short* w3b   = (unsigned short*)p; p += NW2 * 2;
    float* pv1  = (float*)p; p += (size_t)B_ * H_ * 32 * 64 * 4;
    float* pms1 = (float*)p; p += (size_t)B_ * H_ * 32 * 2 * 4;
    float* pv2  = (float*)p; p += (size_t)B_ * H_ * NS2 * 64 * 4;
    float* pms2 = (float*)p; p += (size_t)B_ * H_ * NS2 * 2 * 4;
    float* gq   = (float*)p; p += (size_t)B_ * H_ * 64 * 4;
    float* bvec = (float*)p; p += (size_t)B_ * H_ * 64 * 4;
    float* gkv  = (float*)p; p += (size_t)B_ * H_ * 64 * 4;

    // 1) convert x + Wqk + Wv^T (one kernel)
    constexpr int N4X  = (int)(NXB / 4);
    constexpr int N4XW = N4X + (int)(NWQK / 4);
    constexpr int NTOT = N4XW + (int)(NWV / 4);
    cvt_all<<<NTOT / 256, 256, 0, stream>>>(x, Wqkv, xb, wqkb, wvT, N4X, N4XW);

    // 2) qk = x @ Wqk^T [M,1536] bf16 + fused alpha partials (768 blocks = 3.0 rounds)
    gemm8<0><<<128 * 6, 512, 0, stream>>>(xb, DIM_, wqkb, qkb, w_q, pv1, pms1, QKS, 6);

    // 3) alpha reduce: gq, bvec = gq * w_k
    path_reduce<<<B_ * H_, 64, 0, stream>>>(pv1, pms1, 32, gq, w_k, bvec);

    // 4) beta path partials + reduce
    fused_path<<<B_ * H_ * NS2, 256, 0, stream>>>(qkb, DIM_, bvec, 1, pv2, pms2);
    path_reduce<<<B_ * H_, 64, 0, stream>>>(pv2, pms2, NS2, gkv, nullptr, nullptr);

    // 5) W2[b] = Wp * gk_b (bf16)
    fold_wp<<<(int)(NW2 / 4 / 256), 256, 0, stream>>>(Wp, gkv, w2b);

    // 6) W3[b] = W2[b] @ Wv  (batched 256^2-tile GEMM, 8*9 = 72 blocks)
    gemm8<2><<<72, 512, 0, stream>>>(w2b, DIM_, wvT, w3b, nullptr, nullptr, nullptr,
                                     DIM_, 3);

    // 7) out = x @ W3_b^T + bp + q_flat (768 blocks = 3.0 rounds)
    gemm128<<<256 * 3, 512, 0, stream>>>(xb, DIM_, w3b, out, bp, qkb, DIM_, 3);
}

// Round 9
// 217.389 us; speedup vs baseline: 1.0898x; 1.0898x over previous
//
#include <hip/hip_runtime.h>
#include <hip/hip_bf16.h>
#include <cstdint>
#include <cstddef>

#define B_ 8
#define N_ 4096
#define DIM_ 768
#define H_ 12
#define M_ (B_*N_)        // 32768
#define SCALE_ 0.125f
#define NS2 16
#define KDIM 768
#define NKT 12
#define NITER 6

typedef __attribute__((ext_vector_type(8))) short s8v;
typedef __attribute__((ext_vector_type(4))) float f4v;

__device__ inline float bf2f(unsigned short u) {
    unsigned v = ((unsigned)u) << 16;
    return __builtin_bit_cast(float, v);
}
__device__ inline unsigned short f2bf(float f) {
    unsigned u = __builtin_bit_cast(unsigned, f);
    return (unsigned short)((u + 0x7FFFu + ((u >> 16) & 1u)) >> 16);
}
__device__ inline void gload16(const void* g, void* l) {
    __builtin_amdgcn_global_load_lds(
        (const __attribute__((address_space(1))) void*)g,
        (__attribute__((address_space(3))) void*)l, 16, 0, 0);
}

#define BARX() __builtin_amdgcn_s_barrier()
#define PRIO1() __builtin_amdgcn_s_setprio(1)
#define PRIO0() __builtin_amdgcn_s_setprio(0)
#define VM4() asm volatile("s_waitcnt vmcnt(4)" ::: "memory")
#define VM0() asm volatile("s_waitcnt vmcnt(0)" ::: "memory")

// ---------------- 256x256 8-phase bf16 GEMM: C = A[M,K] @ B[Nc_B,K]^T ----------------
// EPI==0: qk GEMM. q cols (tn<3): NO store, only fused alpha partials.
//         k cols (tn>=3): store bf16 to Cb[row*768 + (tn-3)*256+...].
// EPI==2: batched weight GEMM (9 tiles/batch, ntn=3), A/C offset batch*768^2, B shared.
//         Store = bf16(acc + addW[row*768+col])  (folds Wq into W4).
template<int EPI>
__global__ __launch_bounds__(512, 2)
void gemm8(const unsigned short* __restrict__ A, int ldaE,
           const unsigned short* __restrict__ Bmat,
           unsigned short* __restrict__ Cb,
           const float* __restrict__ w_q,
           float* __restrict__ pv1, float* __restrict__ pms1,
           const float* __restrict__ addW,
           int ntn)
{
    __shared__ __align__(16) char smem[131072];   // 2 bufs x 4 regions x 16KB
    const int tid = threadIdx.x;
    const int l = tid & 63, w = tid >> 6;
    const int lr = l & 15, g = l >> 4;
    const int wm = w >> 2, wn = w & 3;

    const int nwg = gridDim.x, cpx = nwg >> 3;
    const int bid = blockIdx.x;
    int lg = (bid & 7) * cpx + (bid >> 3);

    size_t batch_off = 0;
    if (EPI == 2) {
        const int bb = lg / 9;
        lg -= bb * 9;
        batch_off = (size_t)bb * (DIM_ * DIM_);
    }
    const int tm = lg / ntn, tn = lg % ntn;
    const int m0 = tm * 256, n0 = tn * 256;

    const long ldaB = (long)ldaE * 2;
    const long ldbB = (long)KDIM * 2;

    const int srA = w * 8 + (l >> 3);
    const int kbs = (l & 7) * 16;
    const int kbx = kbs ^ ((srA & 7) << 4);
    long offA[2], offB[2];
    offA[0] = (long)(srA) * ldaB + kbx;
    offA[1] = (long)(128 + srA) * ldaB + kbx;
    offB[0] = (long)(((srA >> 5)) * 64 + (srA & 31)) * ldbB + kbx;
    offB[1] = (long)((2 + (srA >> 5)) * 64 + (srA & 31)) * ldbB + kbx;

    const char* Abase = (const char*)(A + batch_off + (size_t)m0 * ldaE);
    const char* Bbase = (const char*)(Bmat + (size_t)n0 * KDIM);

    const int aoff = (wm * 64 + lr) * 128;
    const int boff = (wn * 32 + lr) * 128;
    const int kx0 = (g * 16) ^ ((lr & 7) << 4);
    const int kx1 = (64 + g * 16) ^ ((lr & 7) << 4);

    f4v acc[8][4] = {};
    s8v af[4][2];
    s8v bfr[2][2][2];

#define STG_A(buf_, qm_, kt_) { \
    const char* s0_ = Abase + (long)(kt_) * 2 + (long)(qm_) * 64 * ldaB; \
    char* d0_ = smem + ((buf_) * 4 + (qm_)) * 16384 + w * 1024; \
    gload16(s0_ + offA[0], d0_); \
    gload16(s0_ + offA[1], d0_ + 8192); }

#define STG_B(buf_, qn_, kt_) { \
    const char* s0_ = Bbase + (long)(kt_) * 2 + (long)(qn_) * 32 * ldbB; \
    char* d0_ = smem + ((buf_) * 4 + 2 + (qn_)) * 16384 + w * 1024; \
    gload16(s0_ + offB[0], d0_); \
    gload16(s0_ + offB[1], d0_ + 8192); }

#define DS_A(buf_, qm_) { \
    const char* ba_ = smem + ((buf_) * 4 + (qm_)) * 16384 + aoff; \
    af[0][0] = *(const s8v*)(ba_ +    0 + kx0); af[0][1] = *(const s8v*)(ba_ +    0 + kx1); \
    af[1][0] = *(const s8v*)(ba_ + 2048 + kx0); af[1][1] = *(const s8v*)(ba_ + 2048 + kx1); \
    af[2][0] = *(const s8v*)(ba_ + 4096 + kx0); af[2][1] = *(const s8v*)(ba_ + 4096 + kx1); \
    af[3][0] = *(const s8v*)(ba_ + 6144 + kx0); af[3][1] = *(const s8v*)(ba_ + 6144 + kx1); }

#define DS_B(buf_, qn_) { \
    const char* bb_ = smem + ((buf_) * 4 + 2 + (qn_)) * 16384 + boff; \
    bfr[qn_][0][0] = *(const s8v*)(bb_ +    0 + kx0); bfr[qn_][0][1] = *(const s8v*)(bb_ +    0 + kx1); \
    bfr[qn_][1][0] = *(const s8v*)(bb_ + 2048 + kx0); bfr[qn_][1][1] = *(const s8v*)(bb_ + 2048 + kx1); }

#define MM(fmg_, fng_, qn_, kk_) \
    acc[fmg_][fng_] = __builtin_amdgcn_mfma_f32_16x16x32_bf16(af[(fmg_)&3][kk_], bfr[qn_][(fng_)&1][kk_], acc[fmg_][fng_], 0, 0, 0);

#define MFMA8(qm_, qn_, kk_) \
    MM((qm_)*4+0, (qn_)*2+0, qn_, kk_) MM((qm_)*4+0, (qn_)*2+1, qn_, kk_) \
    MM((qm_)*4+1, (qn_)*2+0, qn_, kk_) MM((qm_)*4+1, (qn_)*2+1, qn_, kk_) \
    MM((qm_)*4+2, (qn_)*2+0, qn_, kk_) MM((qm_)*4+2, (qn_)*2+1, qn_, kk_) \
    MM((qm_)*4+3, (qn_)*2+0, qn_, kk_) MM((qm_)*4+3, (qn_)*2+1, qn_, kk_)

#define MFMA16(qm_, qn_) { MFMA8(qm_, qn_, 0) MFMA8(qm_, qn_, 1) }

    STG_A(0, 0, 0); STG_B(0, 0, 0); STG_A(0, 1, 0); STG_B(0, 1, 0);
    STG_A(1, 0, 64); STG_B(1, 0, 64);
    VM4(); BARX();

    for (int i = 0; i < NITER; ++i) {
        const int t1k = (2 * i + 1) * 64, t2k = (2 * i + 2) * 64, t3k = (2 * i + 3) * 64;
        const bool h2 = (2 * i + 2) < NKT, h3 = (2 * i + 3) < NKT;
        const bool last = (i == NITER - 1);
        DS_A(0, 0); DS_B(0, 0); STG_B(1, 1, t1k);
        BARX(); PRIO1(); MFMA16(0, 0); PRIO0(); BARX();
        DS_B(0, 1); STG_A(1, 1, t1k);
        BARX(); PRIO1(); MFMA16(0, 1); PRIO0(); BARX();
        DS_A(0, 1); if (h2) STG_A(0, 0, t2k);
        BARX(); PRIO1(); MFMA16(1, 0); PRIO0(); BARX();
        if (h2) STG_B(0, 0, t2k);
        BARX(); PRIO1(); MFMA16(1, 1); PRIO0();
        if (last) { VM0(); } else { VM4(); }
        BARX();
        DS_A(1, 0); DS_B(1, 0); if (h2) STG_A(0, 1, t2k);
        BARX(); PRIO1(); MFMA16(0, 0); PRIO0(); BARX();
        DS_B(1, 1); if (h2) STG_B(0, 1, t2k);
        BARX(); PRIO1(); MFMA16(0, 1); PRIO0(); BARX();
        DS_A(1, 1); if (h3) STG_A(1, 0, t3k);
        BARX(); PRIO1(); MFMA16(1, 0); PRIO0(); BARX();
        if (h3) STG_B(1, 0, t3k);
        BARX(); PRIO1(); MFMA16(1, 1); PRIO0();
        if (last) { VM0(); } else { VM4(); }
        BARX();
    }

    if (EPI == 0) {
        // store k tiles only
        if (tn >= 3) {
            const int c0 = (tn - 3) * 256;
#pragma unroll
            for (int fmg = 0; fmg < 8; ++fmg) {
#pragma unroll
                for (int fng = 0; fng < 4; ++fng) {
                    const int col = c0 + wn * 64 + fng * 16 + lr;
#pragma unroll
                    for (int r = 0; r < 4; ++r) {
                        const int row = m0 + wm * 128 + fmg * 16 + g * 4 + r;
                        Cb[(size_t)row * DIM_ + col] = f2bf(acc[fmg][fng][r]);
                    }
                }
            }
        }
    } else {
        // W4 = bf16(W3 + Wq)
#pragma unroll
        for (int fmg = 0; fmg < 8; ++fmg) {
#pragma unroll
            for (int fng = 0; fng < 4; ++fng) {
                const int col = n0 + wn * 64 + fng * 16 + lr;
#pragma unroll
                for (int r = 0; r < 4; ++r) {
                    const int row = m0 + wm * 128 + fmg * 16 + g * 4 + r;
                    Cb[batch_off + (size_t)row * DIM_ + col] =
                        f2bf(acc[fmg][fng][r] + addW[(size_t)row * DIM_ + col]);
                }
            }
        }
    }

    // fused alpha partials: q columns only (tn<3); each wave = one head x 128 rows
    if (EPI == 0 && tn < 3) {
        const int h = tn * 4 + wn;
        float wq[4];
#pragma unroll
        for (int f = 0; f < 4; ++f) wq[f] = w_q[h * 64 + f * 16 + lr];

        float d[8][4];
#pragma unroll
        for (int fmg = 0; fmg < 8; ++fmg) {
#pragma unroll
            for (int r = 0; r < 4; ++r) {
                float s = acc[fmg][0][r] * wq[0] + acc[fmg][1][r] * wq[1]
                        + acc[fmg][2][r] * wq[2] + acc[fmg][3][r] * wq[3];
                s += __shfl_xor(s, 1); s += __shfl_xor(s, 2);
                s += __shfl_xor(s, 4); s += __shfl_xor(s, 8);
                d[fmg][r] = s * SCALE_;
            }
        }
        float mw = d[0][0];
#pragma unroll
        for (int fmg = 0; fmg < 8; ++fmg)
#pragma unroll
            for (int r = 0; r < 4; ++r) mw = fmaxf(mw, d[fmg][r]);
        mw = fmaxf(mw, __shfl_xor(mw, 16));
        mw = fmaxf(mw, __shfl_xor(mw, 32));

        float ssum = 0.f;
        float pvec[4] = {};
#pragma unroll
        for (int fmg = 0; fmg < 8; ++fmg) {
#pragma unroll
            for (int r = 0; r < 4; ++r) {
                const float e = __expf(d[fmg][r] - mw);
                ssum += e;
#pragma unroll
                for (int f = 0; f < 4; ++f) pvec[f] += e * acc[fmg][f][r];
            }
        }
        ssum += __shfl_xor(ssum, 16); ssum += __shfl_xor(ssum, 32);
#pragma unroll
        for (int f = 0; f < 4; ++f) {
            pvec[f] += __shfl_xor(pvec[f], 16);
            pvec[f] += __shfl_xor(pvec[f], 32);
        }

        const int b = m0 >> 12;
        const int bh = b * H_ + h;
        const int slice = ((m0 & (N_ - 1)) >> 7) + wm;   // 32 slices per bh
        if (g == 0) {
#pragma unroll
            for (int f = 0; f < 4; ++f)
                pv1[(size_t)(bh * 32 + slice) * 64 + f * 16 + lr] = pvec[f];
            if (lr == 0) {
                pms1[(bh * 32 + slice) * 2] = mw;
                pms1[(bh * 32 + slice) * 2 + 1] = ssum;
            }
        }
    }
#undef STG_A
#undef STG_B
#undef DS_A
#undef DS_B
#undef MM
#undef MFMA8
#undef MFMA16
}

// ---------------- 128x256 4-phase bf16 GEMM, f32 epilogue (out GEMM) ----------------
// Cf[row,col] = A@B_b^T + bias[col]; B_b per batch (row/4096).
__global__ __launch_bounds__(512, 2)
void gemm128(const unsigned short* __restrict__ A, int ldaE,
             const unsigned short* __restrict__ Bmat,
             float* __restrict__ Cf,
             const float* __restrict__ bias,
             int Nc, int ntn)
{
    __shared__ __align__(16) char smem[98304];
    const int tid = threadIdx.x;
    const int l = tid & 63, w = tid >> 6;
    const int lr = l & 15, g = l >> 4;
    const int wm = w >> 2, wn = w & 3;

    const int nwg = gridDim.x, cpx = nwg >> 3;
    const int bid = blockIdx.x;
    const int lg = (bid & 7) * cpx + (bid >> 3);
    const int tm = lg / ntn, tn = lg % ntn;
    const int m0 = tm * 128, n0 = tn * 256;

    const long ldaB = (long)ldaE * 2;
    const long ldbB = (long)KDIM * 2;

    const unsigned short* Bp = Bmat + (size_t)(m0 >> 12) * (DIM_ * DIM_);

    const int srA = w * 8 + (l >> 3);
    const int kbs = (l & 7) * 16;
    const int kbx = kbs ^ ((srA & 7) << 4);
    long offA[2], offB[2];
    offA[0] = (long)(srA) * ldaB + kbx;
    offA[1] = (long)(64 + srA) * ldaB + kbx;
    offB[0] = (long)(((srA >> 5)) * 64 + (srA & 31)) * ldbB + kbx;
    offB[1] = (long)((2 + (srA >> 5)) * 64 + (srA & 31)) * ldbB + kbx;

    const char* Abase = (const char*)(A + (size_t)m0 * ldaE);
    const char* Bbase = (const char*)(Bp + (size_t)n0 * KDIM);

    const int aoff = (wm * 64 + lr) * 128;
    const int boff = (wn * 32 + lr) * 128;
    const int kx0 = (g * 16) ^ ((lr & 7) << 4);
    const int kx1 = (64 + g * 16) ^ ((lr & 7) << 4);

    f4v acc[4][4] = {};
    s8v af[4][2];
    s8v bfr[2][2][2];

#define STG_A1(buf_, kt_) { \
    const char* s0_ = Abase + (long)(kt_) * 2; \
    char* d0_ = smem + ((buf_) * 3) * 16384 + w * 1024; \
    gload16(s0_ + offA[0], d0_); \
    gload16(s0_ + offA[1], d0_ + 8192); }

#define STG_B1(buf_, qn_, kt_) { \
    const char* s0_ = Bbase + (long)(kt_) * 2 + (long)(qn_) * 32 * ldbB; \
    char* d0_ = smem + ((buf_) * 3 + 1 + (qn_)) * 16384 + w * 1024; \
    gload16(s0_ + offB[0], d0_); \
    gload16(s0_ + offB[1], d0_ + 8192); }

#define DS_A1(buf_) { \
    const char* ba_ = smem + ((buf_) * 3) * 16384 + aoff; \
    af[0][0] = *(const s8v*)(ba_ +    0 + kx0); af[0][1] = *(const s8v*)(ba_ +    0 + kx1); \
    af[1][0] = *(const s8v*)(ba_ + 2048 + kx0); af[1][1] = *(const s8v*)(ba_ + 2048 + kx1); \
    af[2][0] = *(const s8v*)(ba_ + 4096 + kx0); af[2][1] = *(const s8v*)(ba_ + 4096 + kx1); \
    af[3][0] = *(const s8v*)(ba_ + 6144 + kx0); af[3][1] = *(const s8v*)(ba_ + 6144 + kx1); }

#define DS_B1(buf_, qn_) { \
    const char* bb_ = smem + ((buf_) * 3 + 1 + (qn_)) * 16384 + boff; \
    bfr[qn_][0][0] = *(const s8v*)(bb_ +    0 + kx0); bfr[qn_][0][1] = *(const s8v*)(bb_ +    0 + kx1); \
    bfr[qn_][1][0] = *(const s8v*)(bb_ + 2048 + kx0); bfr[qn_][1][1] = *(const s8v*)(bb_ + 2048 + kx1); }

#define MM1(fm_, fng_, qn_, kk_) \
    acc[fm_][fng_] = __builtin_amdgcn_mfma_f32_16x16x32_bf16(af[fm_][kk_], bfr[qn_][(fng_)&1][kk_], acc[fm_][fng_], 0, 0, 0);

#define MFMA16_1(qn_, kk_) \
    MM1(0, (qn_)*2+0, qn_, kk_) MM1(0, (qn_)*2+1, qn_, kk_) \
    MM1(1, (qn_)*2+0, qn_, kk_) MM1(1, (qn_)*2+1, qn_, kk_) \
    MM1(2, (qn_)*2+0, qn_, kk_) MM1(2, (qn_)*2+1, qn_, kk_) \
    MM1(3, (qn_)*2+0, qn_, kk_) MM1(3, (qn_)*2+1, qn_, kk_)

#define MFMA32_1(qn_) { MFMA16_1(qn_, 0) MFMA16_1(qn_, 1) }

    STG_A1(0, 0); STG_B1(0, 0, 0); STG_B1(0, 1, 0);
    STG_A1(1, 64); STG_B1(1, 0, 64);
    VM4(); BARX();

    for (int i = 0; i < NITER; ++i) {
        const int t1k = (2 * i + 1) * 64, t2k = (2 * i + 2) * 64, t3k = (2 * i + 3) * 64;
        const bool h2 = (2 * i + 2) < NKT, h3 = (2 * i + 3) < NKT;
        const bool last = (i == NITER - 1);
        DS_A1(0); DS_B1(0, 0); STG_B1(1, 1, t1k);
        BARX(); PRIO1(); MFMA32_1(0); PRIO0(); BARX();
        DS_B1(0, 1); if (h2) { STG_A1(0, t2k); STG_B1(0, 0, t2k); }
        BARX(); PRIO1(); MFMA32_1(1); PRIO0();
        if (last) { VM0(); } else { VM4(); }
        BARX();
        DS_A1(1); DS_B1(1, 0); if (h2) STG_B1(0, 1, t2k);
        BARX(); PRIO1(); MFMA32_1(0); PRIO0(); BARX();
        DS_B1(1, 1); if (h3) { STG_A1(1, t3k); STG_B1(1, 0, t3k); }
        BARX(); PRIO1(); MFMA32_1(1); PRIO0();
        if (last) { VM0(); } else { VM4(); }
        BARX();
    }

#pragma unroll
    for (int fm = 0; fm < 4; ++fm) {
#pragma unroll
        for (int fng = 0; fng < 4; ++fng) {
            const int col = n0 + wn * 64 + fng * 16 + lr;
#pragma unroll
            for (int r = 0; r < 4; ++r) {
                const int row = m0 + wm * 64 + fm * 16 + g * 4 + r;
                Cf[(size_t)row * Nc + col] = acc[fm][fng][r] + bias[col];
            }
        }
    }
#undef STG_A1
#undef STG_B1
#undef DS_A1
#undef DS_B1
#undef MM1
#undef MFMA16_1
#undef MFMA32_1
}

// ---------------- beta path: inlines alpha reduce (cooperative), emits beta partials --
__global__ __launch_bounds__(256)
void fused_b(const unsigned short* __restrict__ kb,
             const float* __restrict__ pv1, const float* __restrict__ pms1,
             const float* __restrict__ w_k,
             float* __restrict__ pv2, float* __restrict__ pms2)
{
    const int bid = blockIdx.x;
    const int bh = bid / NS2, sp = bid % NS2;
    const int b = bh / H_, h = bh % H_;
    const int t = threadIdx.x;
    const int lane8 = t & 7, grp = t >> 3;

    // cooperative alpha reduce -> gq_s[c] = global_q[c] * w_k[h][c]
    __shared__ float gq_s[64];
    if (t < 64) {
        float mstar = pms1[(bh * 32) * 2];
#pragma unroll
        for (int p = 1; p < 32; ++p) mstar = fmaxf(mstar, pms1[(bh * 32 + p) * 2]);
        float sstar = 0.f, v = 0.f;
#pragma unroll
        for (int p = 0; p < 32; ++p) {
            const float e = __expf(pms1[(bh * 32 + p) * 2] - mstar);
            sstar += pms1[(bh * 32 + p) * 2 + 1] * e;
            v += pv1[(size_t)(bh * 32 + p) * 64 + t] * e;
        }
        gq_s[t] = (v / sstar) * w_k[h * 64 + t];
    }
    __syncthreads();

    float w8[8];
#pragma unroll
    for (int j = 0; j < 8; j++) w8[j] = gq_s[lane8 * 8 + j];

    const unsigned short* base = kb + ((size_t)(b * N_ + sp * 256) * DIM_)
                                 + h * 64 + lane8 * 8;
    float q[8][8];
    float d[8];
#pragma unroll
    for (int pass = 0; pass < 8; ++pass) {
        const int row = pass * 32 + grp;
        s8v q8 = *(const s8v*)(base + (size_t)row * DIM_);
        float s = 0.f;
#pragma unroll
        for (int j = 0; j < 8; j++) {
            q[pass][j] = bf2f((unsigned short)q8[j]);
            s += q[pass][j] * w8[j];
        }
        s += __shfl_xor(s, 1); s += __shfl_xor(s, 2); s += __shfl_xor(s, 4);
        d[pass] = s * SCALE_;
    }
    float m = d[0];
#pragma unroll
    for (int pass = 1; pass < 8; ++pass) m = fmaxf(m, d[pass]);
    float ssum = 0.f;
    float a8[8] = {};
#pragma unroll
    for (int pass = 0; pass < 8; ++pass) {
        float e = __expf(d[pass] - m);
        ssum += e;
#pragma unroll
        for (int j = 0; j < 8; j++) a8[j] += e * q[pass][j];
    }

    __shared__ float Lm[32], Ls[32];
    __shared__ float La[32][64];
    if (lane8 == 0) { Lm[grp] = m; Ls[grp] = ssum; }
#pragma unroll
    for (int j = 0; j < 8; j++) La[grp][lane8 * 8 + j] = a8[j];
    __syncthreads();

    if (t < 64) {
        float mstar = Lm[0];
#pragma unroll
        for (int g2 = 1; g2 < 32; ++g2) mstar = fmaxf(mstar, Lm[g2]);
        float sstar = 0.f, v = 0.f;
#pragma unroll
        for (int g2 = 0; g2 < 32; ++g2) {
            float e = __expf(Lm[g2] - mstar);
            sstar += Ls[g2] * e;
            v += La[g2][t] * e;
        }
        pv2[(size_t)bid * 64 + t] = v;
        if (t == 0) { pms2[bid * 2] = mstar; pms2[bid * 2 + 1] = sstar; }
    }
}

// combine nsp partials per bh -> gout[bh][64]
__global__ void path_reduce(const float* __restrict__ partv, const float* __restrict__ partms,
                            int nsp, float* __restrict__ gout)
{
    const int bh = blockIdx.x;
    const int t = threadIdx.x;   // 64
    float mstar = partms[(bh * nsp) * 2];
    for (int p = 1; p < nsp; ++p) mstar = fmaxf(mstar, partms[(bh * nsp + p) * 2]);
    float sstar = 0.f, v = 0.f;
    for (int p = 0; p < nsp; ++p) {
        float e = __expf(partms[(bh * nsp + p) * 2] - mstar);
        sstar += partms[(bh * nsp + p) * 2 + 1] * e;
        v += partv[(size_t)(bh * nsp + p) * 64 + t] * e;
    }
    gout[bh * 64 + t] = v / sstar;
}

// ---------------- conversion: x -> xb, Wqk -> wqkb, Wv -> wvT (transposed) ----------
__global__ void cvt_all(const float* __restrict__ x, const float* __restrict__ Wqkv,
                        unsigned short* __restrict__ xb, unsigned short* __restrict__ wqkb,
                        unsigned short* __restrict__ wvT,
                        int n4x, int n4xw)
{
    int i = blockIdx.x * 256 + threadIdx.x;
    if (i < n4xw) {
        const float* src; unsigned short* dst; int k;
        if (i < n4x) { src = x; dst = xb; k = i; }
        else { src = Wqkv; dst = wqkb; k = i - n4x; }
        float4 v = ((const float4*)src)[k];
        ushort4 o;
        o.x = f2bf(v.x); o.y = f2bf(v.y); o.z = f2bf(v.z); o.w = f2bf(v.w);
        ((ushort4*)dst)[k] = o;
    } else {
        const int k = i - n4xw;
        const int ii = k % DIM_;
        const int c0 = (k / DIM_) * 4;
        ushort4 o;
        o.x = f2bf(Wqkv[(size_t)(2 * DIM_ + c0 + 0) * DIM_ + ii]);
        o.y = f2bf(Wqkv[(size_t)(2 * DIM_ + c0 + 1) * DIM_ + ii]);
        o.z = f2bf(Wqkv[(size_t)(2 * DIM_ + c0 + 2) * DIM_ + ii]);
        o.w = f2bf(Wqkv[(size_t)(2 * DIM_ + c0 + 3) * DIM_ + ii]);
        *(ushort4*)&wvT[(size_t)ii * DIM_ + c0] = o;
    }
}

// ---------------- fold gk into Wp: W2[b][j][c] = bf16(Wp[j][c] * gk[b*768+c]) --------
__global__ __launch_bounds__(256)
void fold_wp(const float* __restrict__ Wp, const float* __restrict__ gk,
             unsigned short* __restrict__ W2)
{
    int idx = blockIdx.x * 256 + threadIdx.x;
    int e4 = idx * 4;
    int b = (int)((unsigned)e4 / (unsigned)(DIM_ * DIM_));
    int rem = e4 - b * (DIM_ * DIM_);
    int c = rem % DIM_;
    float4 wv = *(const float4*)&Wp[rem];
    const float* gp = &gk[b * DIM_ + c];
    ushort4 o;
    o.x = f2bf(wv.x * gp[0]); o.y = f2bf(wv.y * gp[1]);
    o.z = f2bf(wv.z * gp[2]); o.w = f2bf(wv.w * gp[3]);
    *(ushort4*)&W2[e4] = o;
}

extern "C" void kernel_launch(void* const* d_in, const int* in_sizes, int n_in,
                              void* d_out, int out_size, void* d_ws, size_t ws_size,
                              hipStream_t stream)
{
    const float* x    = (const float*)d_in[0];
    const float* Wqkv = (const float*)d_in[1];
    const float* Wp   = (const float*)d_in[2];
    const float* bp   = (const float*)d_in[3];
    const float* w_q  = (const float*)d_in[4];
    const float* w_k  = (const float*)d_in[5];
    float* out = (float*)d_out;

    constexpr size_t NXB  = (size_t)M_ * DIM_;
    constexpr size_t NWQK = (size_t)2 * DIM_ * DIM_;
    constexpr size_t NWV  = (size_t)DIM_ * DIM_;
    constexpr size_t NKB  = (size_t)M_ * DIM_;
    constexpr size_t NW2  = (size_t)B_ * DIM_ * DIM_;

    char* p = (char*)d_ws;
    unsigned short* xb    = (unsigned short*)p; p += NXB * 2;
    unsigned short* wqkb  = (unsigned short*)p; p += NWQK * 2;
    unsigned short* wvT   = (unsigned short*)p; p += NWV * 2;
    unsigned short* kb    = (unsigned short*)p; p += NKB * 2;
    unsigned short* w2b   = (unsigned short*)p; p += NW2 * 2;
    unsigned short* w4b   = (unsigned short*)p; p += NW2 * 2;
    float* pv1  = (float*)p; p += (size_t)B_ * H_ * 32 * 64 * 4;
    float* pms1 = (float*)p; p += (size_t)B_ * H_ * 32 * 2 * 4;
    float* pv2  = (float*)p; p += (size_t)B_ * H_ * NS2 * 64 * 4;
    float* pms2 = (float*)p; p += (size_t)B_ * H_ * NS2 * 2 * 4;
    float* gkv  = (float*)p; p += (size_t)B_ * H_ * 64 * 4;

    // 1) convert x + Wqk + Wv^T (one kernel)
    constexpr int N4X  = (int)(NXB / 4);
    constexpr int N4XW = N4X + (int)(NWQK / 4);
    constexpr int NTOT = N4XW + (int)(NWV / 4);
    cvt_all<<<NTOT / 256, 256, 0, stream>>>(x, Wqkv, xb, wqkb, wvT, N4X, N4XW);

    // 2) qk GEMM: stores k only [M,768] + fused alpha partials (768 blocks)
    gemm8<0><<<128 * 6, 512, 0, stream>>>(xb, DIM_, wqkb, kb, w_q, pv1, pms1,
                                          nullptr, 6);

    // 3) beta path partials (inlines alpha reduce cooperatively)
    fused_b<<<B_ * H_ * NS2, 256, 0, stream>>>(kb, pv1, pms1, w_k, pv2, pms2);

    // 4) beta reduce -> gkv
    path_reduce<<<B_ * H_, 64, 0, stream>>>(pv2, pms2, NS2, gkv);

    // 5) W2[b] = Wp * gk_b (bf16)
    fold_wp<<<(int)(NW2 / 4 / 256), 256, 0, stream>>>(Wp, gkv, w2b);

    // 6) W4[b] = W2[b] @ Wv + Wq  (batched 256^2 GEMM, 72 blocks; folds q_flat)
    gemm8<2><<<72, 512, 0, stream>>>(w2b, DIM_, wvT, w4b, nullptr, nullptr, nullptr,
                                     Wqkv, 3);

    // 7) out = x @ W4_b^T + bp   (768 blocks)
    gemm128<<<256 * 3, 512, 0, stream>>>(xb, DIM_, w4b, out, bp, DIM_, 3);
}

// Round 10
// 206.886 us; speedup vs baseline: 1.1451x; 1.0508x over previous
//
#include <hip/hip_runtime.h>
#include <hip/hip_bf16.h>
#include <cstdint>
#include <cstddef>

#define B_ 8
#define N_ 4096
#define DIM_ 768
#define H_ 12
#define M_ (B_*N_)        // 32768
#define SCALE_ 0.125f
#define NS2 16
#define KDIM 768
#define NKT 12
#define NITER 6

typedef __attribute__((ext_vector_type(8))) short s8v;
typedef __attribute__((ext_vector_type(4))) float f4v;

__device__ inline float bf2f(unsigned short u) {
    unsigned v = ((unsigned)u) << 16;
    return __builtin_bit_cast(float, v);
}
__device__ inline unsigned short f2bf(float f) {
    unsigned u = __builtin_bit_cast(unsigned, f);
    return (unsigned short)((u + 0x7FFFu + ((u >> 16) & 1u)) >> 16);
}
__device__ inline void gload16(const void* g, void* l) {
    __builtin_amdgcn_global_load_lds(
        (const __attribute__((address_space(1))) void*)g,
        (__attribute__((address_space(3))) void*)l, 16, 0, 0);
}

#define BARX() __builtin_amdgcn_s_barrier()
#define PRIO1() __builtin_amdgcn_s_setprio(1)
#define PRIO0() __builtin_amdgcn_s_setprio(0)
#define VM4() asm volatile("s_waitcnt vmcnt(4)" ::: "memory")
#define VM0() asm volatile("s_waitcnt vmcnt(0)" ::: "memory")

// ---------------- 256x256 8-phase bf16 GEMM: qk GEMM ----------------
// q cols (tn<3): NO store, only fused alpha partials.
// k cols (tn>=3): store bf16 to Cb[row*768 + (tn-3)*256+...].
__global__ __launch_bounds__(512, 2)
void gemm8(const unsigned short* __restrict__ A, int ldaE,
           const unsigned short* __restrict__ Bmat,
           unsigned short* __restrict__ Cb,
           const float* __restrict__ w_q,
           float* __restrict__ pv1, float* __restrict__ pms1,
           int ntn)
{
    __shared__ __align__(16) char smem[131072];   // 2 bufs x 4 regions x 16KB
    const int tid = threadIdx.x;
    const int l = tid & 63, w = tid >> 6;
    const int lr = l & 15, g = l >> 4;
    const int wm = w >> 2, wn = w & 3;

    const int nwg = gridDim.x, cpx = nwg >> 3;
    const int bid = blockIdx.x;
    const int lg = (bid & 7) * cpx + (bid >> 3);
    const int tm = lg / ntn, tn = lg % ntn;
    const int m0 = tm * 256, n0 = tn * 256;

    const long ldaB = (long)ldaE * 2;
    const long ldbB = (long)KDIM * 2;

    const int srA = w * 8 + (l >> 3);
    const int kbs = (l & 7) * 16;
    const int kbx = kbs ^ ((srA & 7) << 4);
    long offA[2], offB[2];
    offA[0] = (long)(srA) * ldaB + kbx;
    offA[1] = (long)(128 + srA) * ldaB + kbx;
    offB[0] = (long)(((srA >> 5)) * 64 + (srA & 31)) * ldbB + kbx;
    offB[1] = (long)((2 + (srA >> 5)) * 64 + (srA & 31)) * ldbB + kbx;

    const char* Abase = (const char*)(A + (size_t)m0 * ldaE);
    const char* Bbase = (const char*)(Bmat + (size_t)n0 * KDIM);

    const int aoff = (wm * 64 + lr) * 128;
    const int boff = (wn * 32 + lr) * 128;
    const int kx0 = (g * 16) ^ ((lr & 7) << 4);
    const int kx1 = (64 + g * 16) ^ ((lr & 7) << 4);

    f4v acc[8][4] = {};
    s8v af[4][2];
    s8v bfr[2][2][2];

#define STG_A(buf_, qm_, kt_) { \
    const char* s0_ = Abase + (long)(kt_) * 2 + (long)(qm_) * 64 * ldaB; \
    char* d0_ = smem + ((buf_) * 4 + (qm_)) * 16384 + w * 1024; \
    gload16(s0_ + offA[0], d0_); \
    gload16(s0_ + offA[1], d0_ + 8192); }

#define STG_B(buf_, qn_, kt_) { \
    const char* s0_ = Bbase + (long)(kt_) * 2 + (long)(qn_) * 32 * ldbB; \
    char* d0_ = smem + ((buf_) * 4 + 2 + (qn_)) * 16384 + w * 1024; \
    gload16(s0_ + offB[0], d0_); \
    gload16(s0_ + offB[1], d0_ + 8192); }

#define DS_A(buf_, qm_) { \
    const char* ba_ = smem + ((buf_) * 4 + (qm_)) * 16384 + aoff; \
    af[0][0] = *(const s8v*)(ba_ +    0 + kx0); af[0][1] = *(const s8v*)(ba_ +    0 + kx1); \
    af[1][0] = *(const s8v*)(ba_ + 2048 + kx0); af[1][1] = *(const s8v*)(ba_ + 2048 + kx1); \
    af[2][0] = *(const s8v*)(ba_ + 4096 + kx0); af[2][1] = *(const s8v*)(ba_ + 4096 + kx1); \
    af[3][0] = *(const s8v*)(ba_ + 6144 + kx0); af[3][1] = *(const s8v*)(ba_ + 6144 + kx1); }

#define DS_B(buf_, qn_) { \
    const char* bb_ = smem + ((buf_) * 4 + 2 + (qn_)) * 16384 + boff; \
    bfr[qn_][0][0] = *(const s8v*)(bb_ +    0 + kx0); bfr[qn_][0][1] = *(const s8v*)(bb_ +    0 + kx1); \
    bfr[qn_][1][0] = *(const s8v*)(bb_ + 2048 + kx0); bfr[qn_][1][1] = *(const s8v*)(bb_ + 2048 + kx1); }

#define MM(fmg_, fng_, qn_, kk_) \
    acc[fmg_][fng_] = __builtin_amdgcn_mfma_f32_16x16x32_bf16(af[(fmg_)&3][kk_], bfr[qn_][(fng_)&1][kk_], acc[fmg_][fng_], 0, 0, 0);

#define MFMA8(qm_, qn_, kk_) \
    MM((qm_)*4+0, (qn_)*2+0, qn_, kk_) MM((qm_)*4+0, (qn_)*2+1, qn_, kk_) \
    MM((qm_)*4+1, (qn_)*2+0, qn_, kk_) MM((qm_)*4+1, (qn_)*2+1, qn_, kk_) \
    MM((qm_)*4+2, (qn_)*2+0, qn_, kk_) MM((qm_)*4+2, (qn_)*2+1, qn_, kk_) \
    MM((qm_)*4+3, (qn_)*2+0, qn_, kk_) MM((qm_)*4+3, (qn_)*2+1, qn_, kk_)

#define MFMA16(qm_, qn_) { MFMA8(qm_, qn_, 0) MFMA8(qm_, qn_, 1) }

    STG_A(0, 0, 0); STG_B(0, 0, 0); STG_A(0, 1, 0); STG_B(0, 1, 0);
    STG_A(1, 0, 64); STG_B(1, 0, 64);
    VM4(); BARX();

    for (int i = 0; i < NITER; ++i) {
        const int t1k = (2 * i + 1) * 64, t2k = (2 * i + 2) * 64, t3k = (2 * i + 3) * 64;
        const bool h2 = (2 * i + 2) < NKT, h3 = (2 * i + 3) < NKT;
        const bool last = (i == NITER - 1);
        DS_A(0, 0); DS_B(0, 0); STG_B(1, 1, t1k);
        BARX(); PRIO1(); MFMA16(0, 0); PRIO0(); BARX();
        DS_B(0, 1); STG_A(1, 1, t1k);
        BARX(); PRIO1(); MFMA16(0, 1); PRIO0(); BARX();
        DS_A(0, 1); if (h2) STG_A(0, 0, t2k);
        BARX(); PRIO1(); MFMA16(1, 0); PRIO0(); BARX();
        if (h2) STG_B(0, 0, t2k);
        BARX(); PRIO1(); MFMA16(1, 1); PRIO0();
        if (last) { VM0(); } else { VM4(); }
        BARX();
        DS_A(1, 0); DS_B(1, 0); if (h2) STG_A(0, 1, t2k);
        BARX(); PRIO1(); MFMA16(0, 0); PRIO0(); BARX();
        DS_B(1, 1); if (h2) STG_B(0, 1, t2k);
        BARX(); PRIO1(); MFMA16(0, 1); PRIO0(); BARX();
        DS_A(1, 1); if (h3) STG_A(1, 0, t3k);
        BARX(); PRIO1(); MFMA16(1, 0); PRIO0(); BARX();
        if (h3) STG_B(1, 0, t3k);
        BARX(); PRIO1(); MFMA16(1, 1); PRIO0();
        if (last) { VM0(); } else { VM4(); }
        BARX();
    }

    // store k tiles only
    if (tn >= 3) {
        const int c0 = (tn - 3) * 256;
#pragma unroll
        for (int fmg = 0; fmg < 8; ++fmg) {
#pragma unroll
            for (int fng = 0; fng < 4; ++fng) {
                const int col = c0 + wn * 64 + fng * 16 + lr;
#pragma unroll
                for (int r = 0; r < 4; ++r) {
                    const int row = m0 + wm * 128 + fmg * 16 + g * 4 + r;
                    Cb[(size_t)row * DIM_ + col] = f2bf(acc[fmg][fng][r]);
                }
            }
        }
    }

    // fused alpha partials: q columns only (tn<3); each wave = one head x 128 rows
    if (tn < 3) {
        const int h = tn * 4 + wn;
        float wq[4];
#pragma unroll
        for (int f = 0; f < 4; ++f) wq[f] = w_q[h * 64 + f * 16 + lr];

        float d[8][4];
#pragma unroll
        for (int fmg = 0; fmg < 8; ++fmg) {
#pragma unroll
            for (int r = 0; r < 4; ++r) {
                float s = acc[fmg][0][r] * wq[0] + acc[fmg][1][r] * wq[1]
                        + acc[fmg][2][r] * wq[2] + acc[fmg][3][r] * wq[3];
                s += __shfl_xor(s, 1); s += __shfl_xor(s, 2);
                s += __shfl_xor(s, 4); s += __shfl_xor(s, 8);
                d[fmg][r] = s * SCALE_;
            }
        }
        float mw = d[0][0];
#pragma unroll
        for (int fmg = 0; fmg < 8; ++fmg)
#pragma unroll
            for (int r = 0; r < 4; ++r) mw = fmaxf(mw, d[fmg][r]);
        mw = fmaxf(mw, __shfl_xor(mw, 16));
        mw = fmaxf(mw, __shfl_xor(mw, 32));

        float ssum = 0.f;
        float pvec[4] = {};
#pragma unroll
        for (int fmg = 0; fmg < 8; ++fmg) {
#pragma unroll
            for (int r = 0; r < 4; ++r) {
                const float e = __expf(d[fmg][r] - mw);
                ssum += e;
#pragma unroll
                for (int f = 0; f < 4; ++f) pvec[f] += e * acc[fmg][f][r];
            }
        }
        ssum += __shfl_xor(ssum, 16); ssum += __shfl_xor(ssum, 32);
#pragma unroll
        for (int f = 0; f < 4; ++f) {
            pvec[f] += __shfl_xor(pvec[f], 16);
            pvec[f] += __shfl_xor(pvec[f], 32);
        }

        const int b = m0 >> 12;
        const int bh = b * H_ + h;
        const int slice = ((m0 & (N_ - 1)) >> 7) + wm;   // 32 slices per bh
        if (g == 0) {
#pragma unroll
            for (int f = 0; f < 4; ++f)
                pv1[(size_t)(bh * 32 + slice) * 64 + f * 16 + lr] = pvec[f];
            if (lr == 0) {
                pms1[(bh * 32 + slice) * 2] = mw;
                pms1[(bh * 32 + slice) * 2 + 1] = ssum;
            }
        }
    }
#undef STG_A
#undef STG_B
#undef DS_A
#undef DS_B
#undef MM
#undef MFMA8
#undef MFMA16
}

// ---------------- 128x256 4-phase bf16 GEMM ----------------
// MODE 0: Cf[row,col] = A@B_b^T + bias[col] (f32); B_b per batch (row/4096).
// MODE 1: CbO[row,col] = bf16(A@B^T + addW[(row%768)*768+col]); B shared (wvT).
template<int MODE>
__global__ __launch_bounds__(512, 2)
void gemm128(const unsigned short* __restrict__ A, int ldaE,
             const unsigned short* __restrict__ Bmat,
             float* __restrict__ Cf, unsigned short* __restrict__ CbO,
             const float* __restrict__ bias, const float* __restrict__ addW,
             int Nc, int ntn)
{
    __shared__ __align__(16) char smem[98304];
    const int tid = threadIdx.x;
    const int l = tid & 63, w = tid >> 6;
    const int lr = l & 15, g = l >> 4;
    const int wm = w >> 2, wn = w & 3;

    const int nwg = gridDim.x, cpx = nwg >> 3;
    const int bid = blockIdx.x;
    const int lg = (bid & 7) * cpx + (bid >> 3);
    const int tm = lg / ntn, tn = lg % ntn;
    const int m0 = tm * 128, n0 = tn * 256;

    const long ldaB = (long)ldaE * 2;
    const long ldbB = (long)KDIM * 2;

    const unsigned short* Bp = Bmat;
    if (MODE == 0) Bp = Bmat + (size_t)(m0 >> 12) * (DIM_ * DIM_);

    const int srA = w * 8 + (l >> 3);
    const int kbs = (l & 7) * 16;
    const int kbx = kbs ^ ((srA & 7) << 4);
    long offA[2], offB[2];
    offA[0] = (long)(srA) * ldaB + kbx;
    offA[1] = (long)(64 + srA) * ldaB + kbx;
    offB[0] = (long)(((srA >> 5)) * 64 + (srA & 31)) * ldbB + kbx;
    offB[1] = (long)((2 + (srA >> 5)) * 64 + (srA & 31)) * ldbB + kbx;

    const char* Abase = (const char*)(A + (size_t)m0 * ldaE);
    const char* Bbase = (const char*)(Bp + (size_t)n0 * KDIM);

    const int aoff = (wm * 64 + lr) * 128;
    const int boff = (wn * 32 + lr) * 128;
    const int kx0 = (g * 16) ^ ((lr & 7) << 4);
    const int kx1 = (64 + g * 16) ^ ((lr & 7) << 4);

    f4v acc[4][4] = {};
    s8v af[4][2];
    s8v bfr[2][2][2];

#define STG_A1(buf_, kt_) { \
    const char* s0_ = Abase + (long)(kt_) * 2; \
    char* d0_ = smem + ((buf_) * 3) * 16384 + w * 1024; \
    gload16(s0_ + offA[0], d0_); \
    gload16(s0_ + offA[1], d0_ + 8192); }

#define STG_B1(buf_, qn_, kt_) { \
    const char* s0_ = Bbase + (long)(kt_) * 2 + (long)(qn_) * 32 * ldbB; \
    char* d0_ = smem + ((buf_) * 3 + 1 + (qn_)) * 16384 + w * 1024; \
    gload16(s0_ + offB[0], d0_); \
    gload16(s0_ + offB[1], d0_ + 8192); }

#define DS_A1(buf_) { \
    const char* ba_ = smem + ((buf_) * 3) * 16384 + aoff; \
    af[0][0] = *(const s8v*)(ba_ +    0 + kx0); af[0][1] = *(const s8v*)(ba_ +    0 + kx1); \
    af[1][0] = *(const s8v*)(ba_ + 2048 + kx0); af[1][1] = *(const s8v*)(ba_ + 2048 + kx1); \
    af[2][0] = *(const s8v*)(ba_ + 4096 + kx0); af[2][1] = *(const s8v*)(ba_ + 4096 + kx1); \
    af[3][0] = *(const s8v*)(ba_ + 6144 + kx0); af[3][1] = *(const s8v*)(ba_ + 6144 + kx1); }

#define DS_B1(buf_, qn_) { \
    const char* bb_ = smem + ((buf_) * 3 + 1 + (qn_)) * 16384 + boff; \
    bfr[qn_][0][0] = *(const s8v*)(bb_ +    0 + kx0); bfr[qn_][0][1] = *(const s8v*)(bb_ +    0 + kx1); \
    bfr[qn_][1][0] = *(const s8v*)(bb_ + 2048 + kx0); bfr[qn_][1][1] = *(const s8v*)(bb_ + 2048 + kx1); }

#define MM1(fm_, fng_, qn_, kk_) \
    acc[fm_][fng_] = __builtin_amdgcn_mfma_f32_16x16x32_bf16(af[fm_][kk_], bfr[qn_][(fng_)&1][kk_], acc[fm_][fng_], 0, 0, 0);

#define MFMA16_1(qn_, kk_) \
    MM1(0, (qn_)*2+0, qn_, kk_) MM1(0, (qn_)*2+1, qn_, kk_) \
    MM1(1, (qn_)*2+0, qn_, kk_) MM1(1, (qn_)*2+1, qn_, kk_) \
    MM1(2, (qn_)*2+0, qn_, kk_) MM1(2, (qn_)*2+1, qn_, kk_) \
    MM1(3, (qn_)*2+0, qn_, kk_) MM1(3, (qn_)*2+1, qn_, kk_)

#define MFMA32_1(qn_) { MFMA16_1(qn_, 0) MFMA16_1(qn_, 1) }

    STG_A1(0, 0); STG_B1(0, 0, 0); STG_B1(0, 1, 0);
    STG_A1(1, 64); STG_B1(1, 0, 64);
    VM4(); BARX();

    for (int i = 0; i < NITER; ++i) {
        const int t1k = (2 * i + 1) * 64, t2k = (2 * i + 2) * 64, t3k = (2 * i + 3) * 64;
        const bool h2 = (2 * i + 2) < NKT, h3 = (2 * i + 3) < NKT;
        const bool last = (i == NITER - 1);
        DS_A1(0); DS_B1(0, 0); STG_B1(1, 1, t1k);
        BARX(); PRIO1(); MFMA32_1(0); PRIO0(); BARX();
        DS_B1(0, 1); if (h2) { STG_A1(0, t2k); STG_B1(0, 0, t2k); }
        BARX(); PRIO1(); MFMA32_1(1); PRIO0();
        if (last) { VM0(); } else { VM4(); }
        BARX();
        DS_A1(1); DS_B1(1, 0); if (h2) STG_B1(0, 1, t2k);
        BARX(); PRIO1(); MFMA32_1(0); PRIO0(); BARX();
        DS_B1(1, 1); if (h3) { STG_A1(1, t3k); STG_B1(1, 0, t3k); }
        BARX(); PRIO1(); MFMA32_1(1); PRIO0();
        if (last) { VM0(); } else { VM4(); }
        BARX();
    }

    const int jb = m0 % DIM_;   // row offset within batch (MODE 1)
#pragma unroll
    for (int fm = 0; fm < 4; ++fm) {
#pragma unroll
        for (int fng = 0; fng < 4; ++fng) {
            const int col = n0 + wn * 64 + fng * 16 + lr;
#pragma unroll
            for (int r = 0; r < 4; ++r) {
                const int ro = wm * 64 + fm * 16 + g * 4 + r;
                const int row = m0 + ro;
                if (MODE == 0) {
                    Cf[(size_t)row * Nc + col] = acc[fm][fng][r] + bias[col];
                } else {
                    CbO[(size_t)row * Nc + col] =
                        f2bf(acc[fm][fng][r] + addW[(size_t)(jb + ro) * DIM_ + col]);
                }
            }
        }
    }
#undef STG_A1
#undef STG_B1
#undef DS_A1
#undef DS_B1
#undef MM1
#undef MFMA16_1
#undef MFMA32_1
}

// ---------------- beta path: inlines alpha reduce (cooperative), emits beta partials --
__global__ __launch_bounds__(256)
void fused_b(const unsigned short* __restrict__ kb,
             const float* __restrict__ pv1, const float* __restrict__ pms1,
             const float* __restrict__ w_k,
             float* __restrict__ pv2, float* __restrict__ pms2)
{
    const int bid = blockIdx.x;
    const int bh = bid / NS2, sp = bid % NS2;
    const int b = bh / H_, h = bh % H_;
    const int t = threadIdx.x;
    const int lane8 = t & 7, grp = t >> 3;

    __shared__ float gq_s[64];
    if (t < 64) {
        float mstar = pms1[(bh * 32) * 2];
#pragma unroll
        for (int p = 1; p < 32; ++p) mstar = fmaxf(mstar, pms1[(bh * 32 + p) * 2]);
        float sstar = 0.f, v = 0.f;
#pragma unroll
        for (int p = 0; p < 32; ++p) {
            const float e = __expf(pms1[(bh * 32 + p) * 2] - mstar);
            sstar += pms1[(bh * 32 + p) * 2 + 1] * e;
            v += pv1[(size_t)(bh * 32 + p) * 64 + t] * e;
        }
        gq_s[t] = (v / sstar) * w_k[h * 64 + t];
    }
    __syncthreads();

    float w8[8];
#pragma unroll
    for (int j = 0; j < 8; j++) w8[j] = gq_s[lane8 * 8 + j];

    const unsigned short* base = kb + ((size_t)(b * N_ + sp * 256) * DIM_)
                                 + h * 64 + lane8 * 8;
    float q[8][8];
    float d[8];
#pragma unroll
    for (int pass = 0; pass < 8; ++pass) {
        const int row = pass * 32 + grp;
        s8v q8 = *(const s8v*)(base + (size_t)row * DIM_);
        float s = 0.f;
#pragma unroll
        for (int j = 0; j < 8; j++) {
            q[pass][j] = bf2f((unsigned short)q8[j]);
            s += q[pass][j] * w8[j];
        }
        s += __shfl_xor(s, 1); s += __shfl_xor(s, 2); s += __shfl_xor(s, 4);
        d[pass] = s * SCALE_;
    }
    float m = d[0];
#pragma unroll
    for (int pass = 1; pass < 8; ++pass) m = fmaxf(m, d[pass]);
    float ssum = 0.f;
    float a8[8] = {};
#pragma unroll
    for (int pass = 0; pass < 8; ++pass) {
        float e = __expf(d[pass] - m);
        ssum += e;
#pragma unroll
        for (int j = 0; j < 8; j++) a8[j] += e * q[pass][j];
    }

    __shared__ float Lm[32], Ls[32];
    __shared__ float La[32][64];
    if (lane8 == 0) { Lm[grp] = m; Ls[grp] = ssum; }
#pragma unroll
    for (int j = 0; j < 8; j++) La[grp][lane8 * 8 + j] = a8[j];
    __syncthreads();

    if (t < 64) {
        float mstar = Lm[0];
#pragma unroll
        for (int g2 = 1; g2 < 32; ++g2) mstar = fmaxf(mstar, Lm[g2]);
        float sstar = 0.f, v = 0.f;
#pragma unroll
        for (int g2 = 0; g2 < 32; ++g2) {
            float e = __expf(Lm[g2] - mstar);
            sstar += Ls[g2] * e;
            v += La[g2][t] * e;
        }
        pv2[(size_t)bid * 64 + t] = v;
        if (t == 0) { pms2[bid * 2] = mstar; pms2[bid * 2 + 1] = sstar; }
    }
}

// combine nsp partials per bh -> gout[bh][64]
__global__ void path_reduce(const float* __restrict__ partv, const float* __restrict__ partms,
                            int nsp, float* __restrict__ gout)
{
    const int bh = blockIdx.x;
    const int t = threadIdx.x;   // 64
    float mstar = partms[(bh * nsp) * 2];
    for (int p = 1; p < nsp; ++p) mstar = fmaxf(mstar, partms[(bh * nsp + p) * 2]);
    float sstar = 0.f, v = 0.f;
    for (int p = 0; p < nsp; ++p) {
        float e = __expf(partms[(bh * nsp + p) * 2] - mstar);
        sstar += partms[(bh * nsp + p) * 2 + 1] * e;
        v += partv[(size_t)(bh * nsp + p) * 64 + t] * e;
    }
    gout[bh * 64 + t] = v / sstar;
}

// ---------------- conversion: x -> xb, Wqk -> wqkb, Wv -> wvT (transposed) ----------
__global__ void cvt_all(const float* __restrict__ x, const float* __restrict__ Wqkv,
                        unsigned short* __restrict__ xb, unsigned short* __restrict__ wqkb,
                        unsigned short* __restrict__ wvT,
                        int n4x, int n4xw)
{
    int i = blockIdx.x * 256 + threadIdx.x;
    if (i < n4xw) {
        const float* src; unsigned short* dst; int k;
        if (i < n4x) { src = x; dst = xb; k = i; }
        else { src = Wqkv; dst = wqkb; k = i - n4x; }
        float4 v = ((const float4*)src)[k];
        ushort4 o;
        o.x = f2bf(v.x); o.y = f2bf(v.y); o.z = f2bf(v.z); o.w = f2bf(v.w);
        ((ushort4*)dst)[k] = o;
    } else {
        const int k = i - n4xw;
        const int ii = k % DIM_;
        const int c0 = (k / DIM_) * 4;
        ushort4 o;
        o.x = f2bf(Wqkv[(size_t)(2 * DIM_ + c0 + 0) * DIM_ + ii]);
        o.y = f2bf(Wqkv[(size_t)(2 * DIM_ + c0 + 1) * DIM_ + ii]);
        o.z = f2bf(Wqkv[(size_t)(2 * DIM_ + c0 + 2) * DIM_ + ii]);
        o.w = f2bf(Wqkv[(size_t)(2 * DIM_ + c0 + 3) * DIM_ + ii]);
        *(ushort4*)&wvT[(size_t)ii * DIM_ + c0] = o;
    }
}

// ---------------- fold gk into Wp: W2[b][j][c] = bf16(Wp[j][c] * gk[b*768+c]) --------
__global__ __launch_bounds__(256)
void fold_wp(const float* __restrict__ Wp, const float* __restrict__ gk,
             unsigned short* __restrict__ W2)
{
    int idx = blockIdx.x * 256 + threadIdx.x;
    int e4 = idx * 4;
    int b = (int)((unsigned)e4 / (unsigned)(DIM_ * DIM_));
    int rem = e4 - b * (DIM_ * DIM_);
    int c = rem % DIM_;
    float4 wv = *(const float4*)&Wp[rem];
    const float* gp = &gk[b * DIM_ + c];
    ushort4 o;
    o.x = f2bf(wv.x * gp[0]); o.y = f2bf(wv.y * gp[1]);
    o.z = f2bf(wv.z * gp[2]); o.w = f2bf(wv.w * gp[3]);
    *(ushort4*)&W2[e4] = o;
}

extern "C" void kernel_launch(void* const* d_in, const int* in_sizes, int n_in,
                              void* d_out, int out_size, void* d_ws, size_t ws_size,
                              hipStream_t stream)
{
    const float* x    = (const float*)d_in[0];
    const float* Wqkv = (const float*)d_in[1];
    const float* Wp   = (const float*)d_in[2];
    const float* bp   = (const float*)d_in[3];
    const float* w_q  = (const float*)d_in[4];
    const float* w_k  = (const float*)d_in[5];
    float* out = (float*)d_out;

    constexpr size_t NXB  = (size_t)M_ * DIM_;
    constexpr size_t NWQK = (size_t)2 * DIM_ * DIM_;
    constexpr size_t NWV  = (size_t)DIM_ * DIM_;
    constexpr size_t NKB  = (size_t)M_ * DIM_;
    constexpr size_t NW2  = (size_t)B_ * DIM_ * DIM_;

    char* p = (char*)d_ws;
    unsigned short* xb    = (unsigned short*)p; p += NXB * 2;
    unsigned short* wqkb  = (unsigned short*)p; p += NWQK * 2;
    unsigned short* wvT   = (unsigned short*)p; p += NWV * 2;
    unsigned short* kb    = (unsigned short*)p; p += NKB * 2;
    unsigned short* w2b   = (unsigned short*)p; p += NW2 * 2;
    unsigned short* w4b   = (unsigned short*)p; p += NW2 * 2;
    float* pv1  = (float*)p; p += (size_t)B_ * H_ * 32 * 64 * 4;
    float* pms1 = (float*)p; p += (size_t)B_ * H_ * 32 * 2 * 4;
    float* pv2  = (float*)p; p += (size_t)B_ * H_ * NS2 * 64 * 4;
    float* pms2 = (float*)p; p += (size_t)B_ * H_ * NS2 * 2 * 4;
    float* gkv  = (float*)p; p += (size_t)B_ * H_ * 64 * 4;

    // 1) convert x + Wqk + Wv^T (one kernel)
    constexpr int N4X  = (int)(NXB / 4);
    constexpr int N4XW = N4X + (int)(NWQK / 4);
    constexpr int NTOT = N4XW + (int)(NWV / 4);
    cvt_all<<<NTOT / 256, 256, 0, stream>>>(x, Wqkv, xb, wqkb, wvT, N4X, N4XW);

    // 2) qk GEMM: stores k only [M,768] + fused alpha partials (768 blocks)
    gemm8<<<128 * 6, 512, 0, stream>>>(xb, DIM_, wqkb, kb, w_q, pv1, pms1, 6);

    // 3) beta path partials (inlines alpha reduce cooperatively)
    fused_b<<<B_ * H_ * NS2, 256, 0, stream>>>(kb, pv1, pms1, w_k, pv2, pms2);

    // 4) beta reduce -> gkv
    path_reduce<<<B_ * H_, 64, 0, stream>>>(pv2, pms2, NS2, gkv);

    // 5) W2[b] = Wp * gk_b (bf16)
    fold_wp<<<(int)(NW2 / 4 / 256), 256, 0, stream>>>(Wp, gkv, w2b);

    // 6) W4 = W2 @ Wv + Wq  (flat [6144,768] GEMM, 48x3 = 144 blocks)
    gemm128<1><<<48 * 3, 512, 0, stream>>>(w2b, DIM_, wvT, nullptr, w4b, nullptr, Wqkv,
                                           DIM_, 3);

    // 7) out = x @ W4_b^T + bp   (768 blocks)
    gemm128<0><<<256 * 3, 512, 0, stream>>>(xb, DIM_, w4b, out, nullptr, bp, nullptr,
                                            DIM_, 3);
}